// Round 4
// baseline (196.984 us; speedup 1.0000x reference)
//
#include <hip/hip_runtime.h>

// Problem constants (from reference)
#define NUM_BLOCKS 1024
#define BLOCK_SIZE 128
#define NUM_HEADS 8
#define HEAD_DIM 128
#define NUM_TOKENS 8192
#define ROW_FLOATS (NUM_HEADS * HEAD_DIM)        // 1024 floats per slot row
#define ROW_F4 (ROW_FLOATS / 4)                  // 256 f32x4 per slot row
#define TOTAL_ROWS (NUM_BLOCKS * BLOCK_SIZE)     // 131072 slot rows

typedef float f32x4 __attribute__((ext_vector_type(4)));  // native vec for nontemporal builtins

// Scatter token ids into the slot->token map (destination slots are unique).
__global__ void kv_map_scatter(const int* __restrict__ bidx,
                               const int* __restrict__ boff,
                               int* __restrict__ map) {
    const int t = blockIdx.x * blockDim.x + threadIdx.x;
    if (t < NUM_TOKENS) {
        map[bidx[t] * BLOCK_SIZE + boff[t]] = t;
    }
}

// Output-driven fused copy, grid-stride. One wave per slot row per iteration;
// 4 waves per block. Each row is 1024 floats = 256 f32x4; each of the 64
// lanes moves 4 f32x4 (64 B).
__global__ void kv_fused_copy(const f32x4* __restrict__ inp,
                              const f32x4* __restrict__ cache,
                              const int* __restrict__ map,
                              f32x4* __restrict__ out) {
    const int lane = threadIdx.x & 63;
    const int row_step = gridDim.x * 4;
    for (int row = blockIdx.x * 4 + (threadIdx.x >> 6); row < TOTAL_ROWS;
         row += row_step) {
        const int tok = map[row];                            // wave-uniform
        const f32x4* __restrict__ src =
            (tok >= 0) ? (inp + (size_t)tok * ROW_F4)
                       : (cache + (size_t)row * ROW_F4);
        f32x4* __restrict__ dst = out + (size_t)row * ROW_F4;
#pragma unroll
        for (int i = 0; i < 4; ++i) {
            f32x4 v = __builtin_nontemporal_load(&src[lane + 64 * i]);
            __builtin_nontemporal_store(v, &dst[lane + 64 * i]);
        }
    }
}

extern "C" void kernel_launch(void* const* d_in, const int* in_sizes, int n_in,
                              void* d_out, int out_size, void* d_ws, size_t ws_size,
                              hipStream_t stream) {
    const float* input = (const float*)d_in[0];        // [8192, 8, 128] fp32
    const float* cache = (const float*)d_in[1];        // [1024, 128, 8, 128] fp32
    const int* block_indices = (const int*)d_in[2];    // [8192] int
    const int* block_offset = (const int*)d_in[3];     // [8192] int
    float* out = (float*)d_out;                        // [1024, 128, 8, 128] fp32
    int* map = (int*)d_ws;                             // 131072 ints (512 KiB)

    // map = -1 everywhere (memset node is graph-capturable; saves a launch)
    hipMemsetAsync(map, 0xFF, TOTAL_ROWS * sizeof(int), stream);
    kv_map_scatter<<<NUM_TOKENS / 256, 256, 0, stream>>>(block_indices,
                                                         block_offset, map);
    // grid-stride main copy: 4096 blocks x 4 waves; each wave walks 8 rows
    kv_fused_copy<<<4096, 256, 0, stream>>>(
        (const f32x4*)input, (const f32x4*)cache, map, (f32x4*)out);
}